// Round 1
// baseline (3817.934 us; speedup 1.0000x reference)
//
#include <hip/hip_runtime.h>

#define DEVI __device__ __forceinline__

constexpr size_t XOUT_ELEMS = (size_t)64 * 512 * 512; // 16,777,216

// ---------------------------------------------------------------------------
// Decode subgraph_sizes: harness may hand us int64 or int32 (jnp.int64 demotes
// to int32 without x64). Detect: under int64 little-endian every odd 32-bit
// word (high word, values < 256) is 0; under int32 the odd words are n2 values
// uniform in [0,256) — P(all 64 zero) ~ 256^-64. Reads stay in first 512 B,
// safe for both layouts.
// ---------------------------------------------------------------------------
__global__ void k_decode(const int* __restrict__ ss, int* __restrict__ ns) {
  int t = threadIdx.x; // 0..63
  int odd = ss[2 * t + 1];
  unsigned long long bal = __ballot(odd == 0);
  bool is64 = (bal == 0xFFFFFFFFFFFFFFFFull);
  if (is64) {
    const long long* s64 = (const long long*)ss;
    ns[2 * t]     = (int)s64[2 * t];
    ns[2 * t + 1] = (int)s64[2 * t + 1];
  } else {
    ns[2 * t]     = ss[2 * t];
    ns[2 * t + 1] = ss[2 * t + 1];
  }
}

// ---------------------------------------------------------------------------
// gt[r][o] = gs_row[r] . W_gfc[:,o] + b_gfc[o],  r in [0,128) (= b*2+k)
// gs_row[r] = global_state + r*512 (since (64,1024) viewed as (128,512))
// ---------------------------------------------------------------------------
__global__ void k_gt(const float* __restrict__ gs, const float* __restrict__ W,
                     const float* __restrict__ bias, float* __restrict__ gt) {
  __shared__ float srow[4][512];
  int r0  = blockIdx.y * 4;
  int col = blockIdx.x * 256 + threadIdx.x;
  for (int i = threadIdx.x; i < 4 * 512; i += 256)
    srow[i >> 9][i & 511] = gs[(size_t)r0 * 512 + i];
  __syncthreads();
  float acc0 = 0.f, acc1 = 0.f, acc2 = 0.f, acc3 = 0.f;
  for (int g = 0; g < 512; ++g) {
    float w = W[(size_t)g * 512 + col];
    acc0 += srow[0][g] * w;
    acc1 += srow[1][g] * w;
    acc2 += srow[2][g] * w;
    acc3 += srow[3][g] * w;
  }
  float bb = bias[col];
  gt[(size_t)(r0 + 0) * 512 + col] = acc0 + bb;
  gt[(size_t)(r0 + 1) * 512 + col] = acc1 + bb;
  gt[(size_t)(r0 + 2) * 512 + col] = acc2 + bb;
  gt[(size_t)(r0 + 3) * 512 + col] = acc3 + bb;
}

// ---------------------------------------------------------------------------
// g_out = relu(BN(gt over 128 rows)) -> d_out tail
// ---------------------------------------------------------------------------
__global__ void k_gbn(const float* __restrict__ gt, const float* __restrict__ gamma,
                      const float* __restrict__ beta, float* __restrict__ gout) {
  int col = blockIdx.x * 64 + threadIdx.x;
  float s = 0.f, q = 0.f;
  for (int r = 0; r < 128; ++r) {
    float v = gt[(size_t)r * 512 + col];
    s += v; q += v * v;
  }
  float m   = s * (1.f / 128.f);
  float var = q * (1.f / 128.f) - m * m;
  float inv = 1.f / sqrtf(var + 1e-5f);
  float g = gamma[col], b = beta[col];
  for (int r = 0; r < 128; ++r) {
    float v = (gt[(size_t)r * 512 + col] - m) * inv * g + b;
    gout[(size_t)r * 512 + col] = fmaxf(v, 0.f);
  }
}

// ---------------------------------------------------------------------------
// GEMM core: C(128x128) tile, 256 threads, 8x8 micro-tile (split 4+4 rows/cols
// so LDS reads are broadcast (A) or 2-way (B) only). BK=16, double-buffered
// LDS (32 KiB), one barrier per K-iter, global prefetch one iter ahead.
// lds layout: As0[16][128] | Bs0[16][128] | As1 | Bs1  (floats)
// ---------------------------------------------------------------------------
template <class LA, class LB>
DEVI void gemm_core(float* lds, LA loadA, LB loadB, int niter, float (&acc)[8][8]) {
  const int tid = threadIdx.x;
  const int tx = tid & 15, ty = tid >> 4;
  const int am = tid >> 2, ak = (tid & 3) << 2;   // A: row am/am+64, k ak..ak+3
  const int bk = tid >> 5, bo = (tid & 31) << 2;  // B: row bk/bk+8, col bo..bo+3

  float* As0 = lds;
  float* Bs0 = lds + 2048;
  float* As1 = lds + 4096;
  float* Bs1 = lds + 6144;

  float4 a0 = loadA(am, ak, 0), a1 = loadA(am + 64, ak, 0);
  float4 b0 = loadB(bk, bo, 0), b1 = loadB(bk + 8, bo, 0);
  {
    float* A = As0; float* Bv = Bs0;
    A[(ak + 0) * 128 + am] = a0.x;
    A[(ak + 1) * 128 + am] = a0.y;
    A[(ak + 2) * 128 + am] = a0.z;
    A[(ak + 3) * 128 + am] = a0.w;
    A[(ak + 0) * 128 + am + 64] = a1.x;
    A[(ak + 1) * 128 + am + 64] = a1.y;
    A[(ak + 2) * 128 + am + 64] = a1.z;
    A[(ak + 3) * 128 + am + 64] = a1.w;
    *(float4*)&Bv[bk * 128 + bo]       = b0;
    *(float4*)&Bv[(bk + 8) * 128 + bo] = b1;
  }
  __syncthreads();

  #pragma unroll 1
  for (int it = 0; it < niter; ++it) {
    const bool more = (it + 1 < niter);
    float4 na0, na1, nb0, nb1;
    if (more) {
      na0 = loadA(am, ak, it + 1);
      na1 = loadA(am + 64, ak, it + 1);
      nb0 = loadB(bk, bo, it + 1);
      nb1 = loadB(bk + 8, bo, it + 1);
    }
    float* A  = (it & 1) ? As1 : As0;
    float* Bv = (it & 1) ? Bs1 : Bs0;
    #pragma unroll
    for (int k = 0; k < 16; ++k) {
      float4 ra0 = *(const float4*)&A[k * 128 + ty * 4];
      float4 ra1 = *(const float4*)&A[k * 128 + 64 + ty * 4];
      float4 rb0 = *(const float4*)&Bv[k * 128 + tx * 4];
      float4 rb1 = *(const float4*)&Bv[k * 128 + 64 + tx * 4];
      float av[8] = {ra0.x, ra0.y, ra0.z, ra0.w, ra1.x, ra1.y, ra1.z, ra1.w};
      float bv[8] = {rb0.x, rb0.y, rb0.z, rb0.w, rb1.x, rb1.y, rb1.z, rb1.w};
      #pragma unroll
      for (int i = 0; i < 8; ++i)
        #pragma unroll
        for (int j = 0; j < 8; ++j)
          acc[i][j] += av[i] * bv[j];
    }
    if (more) {
      float* An = (it & 1) ? As0 : As1;
      float* Bn = (it & 1) ? Bs0 : Bs1;
      An[(ak + 0) * 128 + am] = na0.x;
      An[(ak + 1) * 128 + am] = na0.y;
      An[(ak + 2) * 128 + am] = na0.z;
      An[(ak + 3) * 128 + am] = na0.w;
      An[(ak + 0) * 128 + am + 64] = na1.x;
      An[(ak + 1) * 128 + am + 64] = na1.y;
      An[(ak + 2) * 128 + am + 64] = na1.z;
      An[(ak + 3) * 128 + am + 64] = na1.w;
      *(float4*)&Bn[bk * 128 + bo]       = nb0;
      *(float4*)&Bn[(bk + 8) * 128 + bo] = nb1;
      __syncthreads();
    }
  }
}

// ---------------------------------------------------------------------------
// support[gi,e] = [x[b] | bg[b]] @ W_gc[e]   (512x1024 @ 1024x512)
// grid: (otile=4, mtile=4, e + 4*gi), b = b0+gi
// ---------------------------------------------------------------------------
__global__ __launch_bounds__(256) void k_support(
    const float* __restrict__ x, const float* __restrict__ gt,
    const float* __restrict__ Wgc, const int* __restrict__ ns,
    float* __restrict__ sup, int b0) {
  __shared__ float lds[8192];
  const int otile = blockIdx.x * 128;
  const int row0  = blockIdx.y * 128;
  const int e  = blockIdx.z & 3;
  const int gi = blockIdx.z >> 2;
  const int b  = b0 + gi;
  const int n1  = ns[2 * b];
  const int n12 = n1 + ns[2 * b + 1];
  const float* xb  = x + (size_t)b * 512 * 512;
  const float* wb  = Wgc + (size_t)e * 1024 * 512;
  const float* gtb = gt + (size_t)(2 * b) * 512;

  auto loadA = [=](int m, int kk, int it) -> float4 {
    int k = it * 16 + kk;          // global K in [0,1024)
    int row = row0 + m;
    if (k < 512) return *(const float4*)&xb[(size_t)row * 512 + k];
    if (row < n1)  return *(const float4*)&gtb[k - 512];
    if (row < n12) return *(const float4*)&gtb[512 + (k - 512)];
    return make_float4(0.f, 0.f, 0.f, 0.f);
  };
  auto loadB = [=](int kk, int o, int it) -> float4 {
    int k = it * 16 + kk;
    return *(const float4*)&wb[(size_t)k * 512 + otile + o];
  };

  float acc[8][8];
  #pragma unroll
  for (int i = 0; i < 8; ++i)
    #pragma unroll
    for (int j = 0; j < 8; ++j) acc[i][j] = 0.f;

  gemm_core(lds, loadA, loadB, 64, acc);

  float* sb = sup + (size_t)(gi * 4 + e) * 512 * 512;
  const int tx = threadIdx.x & 15, ty = threadIdx.x >> 4;
  #pragma unroll
  for (int i = 0; i < 8; ++i) {
    int row = row0 + ((i < 4) ? ty * 4 + i : 64 + ty * 4 + (i - 4));
    #pragma unroll
    for (int jb = 0; jb < 2; ++jb) {
      int col = otile + jb * 64 + tx * 4;
      float4 v = make_float4(acc[i][jb * 4 + 0], acc[i][jb * 4 + 1],
                             acc[i][jb * 4 + 2], acc[i][jb * 4 + 3]);
      *(float4*)&sb[(size_t)row * 512 + col] = v;
    }
  }
}

// ---------------------------------------------------------------------------
// x_out_pre[b] = sum_e adj[b,e] @ support[gi,e] + b_gc  -> d_out (pre-BN)
// plus per-column sum/sumsq atomics. grid: (otile=4, ntile=4, gi)
// ---------------------------------------------------------------------------
__global__ __launch_bounds__(256) void k_xout(
    const float* __restrict__ adj, const float* __restrict__ sup,
    const float* __restrict__ bgc, float* __restrict__ out,
    float* __restrict__ gsum, float* __restrict__ gsq, int b0) {
  __shared__ float lds[8192];
  const int otile = blockIdx.x * 128;
  const int row0  = blockIdx.y * 128;
  const int gi = blockIdx.z;
  const int b  = b0 + gi;
  const float* ab = adj + (size_t)b * 4 * 512 * 512;
  const float* sb = sup + (size_t)gi * 4 * 512 * 512;

  auto loadA = [=](int m, int kk, int it) -> float4 {
    int k = it * 16 + kk;          // 0..2047 = e*512 + m
    int e = k >> 9, mm = k & 511;
    int row = row0 + m;
    return *(const float4*)&ab[((size_t)e * 512 + row) * 512 + mm];
  };
  auto loadB = [=](int kk, int o, int it) -> float4 {
    int k = it * 16 + kk;
    int e = k >> 9, mm = k & 511;
    return *(const float4*)&sb[((size_t)e * 512 + mm) * 512 + otile + o];
  };

  float acc[8][8];
  #pragma unroll
  for (int i = 0; i < 8; ++i)
    #pragma unroll
    for (int j = 0; j < 8; ++j) acc[i][j] = 0.f;

  gemm_core(lds, loadA, loadB, 128, acc);

  const int tid = threadIdx.x;
  const int tx = tid & 15, ty = tid >> 4;

  float csum[8], csq[8];
  #pragma unroll
  for (int j = 0; j < 8; ++j) {
    int col = otile + ((j < 4) ? tx * 4 + j : 64 + tx * 4 + (j - 4));
    float bb = bgc[col];
    float s = 0.f, q = 0.f;
    #pragma unroll
    for (int i = 0; i < 8; ++i) {
      acc[i][j] += bb;
      float v = acc[i][j];
      s += v; q += v * v;
    }
    csum[j] = s; csq[j] = q;
  }

  #pragma unroll
  for (int i = 0; i < 8; ++i) {
    int row = row0 + ((i < 4) ? ty * 4 + i : 64 + ty * 4 + (i - 4));
    #pragma unroll
    for (int jb = 0; jb < 2; ++jb) {
      int col = otile + jb * 64 + tx * 4;
      float4 v = make_float4(acc[i][jb * 4 + 0], acc[i][jb * 4 + 1],
                             acc[i][jb * 4 + 2], acc[i][jb * 4 + 3]);
      *(float4*)&out[((size_t)b * 512 + row) * 512 + col] = v;
    }
  }

  // per-column partial stats -> LDS -> global atomics
  __syncthreads();
  if (tid < 256) lds[tid] = 0.f;
  __syncthreads();
  #pragma unroll
  for (int j = 0; j < 8; ++j) {
    int cl = (j < 4) ? tx * 4 + j : 64 + tx * 4 + (j - 4);
    atomicAdd(&lds[cl], csum[j]);
    atomicAdd(&lds[128 + cl], csq[j]);
  }
  __syncthreads();
  if (tid < 128) {
    atomicAdd(&gsum[otile + tid], lds[tid]);
    atomicAdd(&gsq[otile + tid],  lds[128 + tid]);
  }
}

// ---------------------------------------------------------------------------
// In-place BN + mask + relu over pre-BN x_out in d_out.
// ---------------------------------------------------------------------------
__global__ void k_norm(const float* __restrict__ gsum, const float* __restrict__ gsq,
                       const float* __restrict__ gamma, const float* __restrict__ beta,
                       const float* __restrict__ mask, float* __restrict__ out) {
  __shared__ float sc[512], sh[512];
  for (int c = threadIdx.x; c < 512; c += blockDim.x) {
    float m   = gsum[c] * (1.f / 32768.f);
    float var = gsq[c] * (1.f / 32768.f) - m * m;
    float inv = 1.f / sqrtf(var + 1e-5f);
    float g = gamma[c] * inv;
    sc[c] = g;
    sh[c] = beta[c] - m * g;
  }
  __syncthreads();
  size_t i0 = (size_t)blockIdx.x * blockDim.x + threadIdx.x;
  size_t stride = (size_t)gridDim.x * blockDim.x;
  size_t n4 = XOUT_ELEMS / 4;
  for (size_t i = i0; i < n4; i += stride) {
    float4 p = ((const float4*)out)[i];
    int c = (int)((i * 4) & 511);
    size_t row = (i * 4) >> 9;
    float mk = mask[row];
    p.x = fmaxf((p.x * sc[c + 0] + sh[c + 0]) * mk, 0.f);
    p.y = fmaxf((p.y * sc[c + 1] + sh[c + 1]) * mk, 0.f);
    p.z = fmaxf((p.z * sc[c + 2] + sh[c + 2]) * mk, 0.f);
    p.w = fmaxf((p.w * sc[c + 3] + sh[c + 3]) * mk, 0.f);
    ((float4*)out)[i] = p;
  }
}

// ---------------------------------------------------------------------------
extern "C" void kernel_launch(void* const* d_in, const int* in_sizes, int n_in,
                              void* d_out, int out_size, void* d_ws, size_t ws_size,
                              hipStream_t stream) {
  const float* x    = (const float*)d_in[0];
  const float* adj  = (const float*)d_in[1];
  const float* gs   = (const float*)d_in[2];
  const int*   ssz  = (const int*)d_in[3];
  const float* mask = (const float*)d_in[4];
  const float* Wgfc = (const float*)d_in[5];
  const float* bgfc = (const float*)d_in[6];
  const float* Wgc  = (const float*)d_in[7];
  const float* bgc  = (const float*)d_in[8];
  const float* gn   = (const float*)d_in[9];
  const float* btn  = (const float*)d_in[10];
  const float* gg   = (const float*)d_in[11];
  const float* btg  = (const float*)d_in[12];
  float* out = (float*)d_out;

  // workspace layout
  float* gt   = (float*)d_ws;                        // 128*512 f32 = 256 KiB
  int*   ns   = (int*)((char*)d_ws + 262144);        // 128 int32
  float* gsum = (float*)((char*)d_ws + 262656);      // 512 f32
  float* gsq  = gsum + 512;                          // 512 f32
  float* sup  = (float*)((char*)d_ws + (1 << 20));   // support chunk

  const size_t per_b = (size_t)4 * 512 * 512 * 4;    // 4 MiB per batch
  long long avail = (long long)ws_size - (1 << 20);
  int G = (avail > 0) ? (int)(avail / (long long)per_b) : 0;
  if (G < 1) G = 1;
  if (G > 64) G = 64;

  k_decode<<<1, 64, 0, stream>>>(ssz, ns);
  k_gt<<<dim3(2, 32), 256, 0, stream>>>(gs, Wgfc, bgfc, gt);
  k_gbn<<<8, 64, 0, stream>>>(gt, gg, btg, out + XOUT_ELEMS);
  hipMemsetAsync(gsum, 0, 4096, stream);

  for (int b0 = 0; b0 < 64; b0 += G) {
    int gc = 64 - b0; if (gc > G) gc = G;
    k_support<<<dim3(4, 4, 4 * gc), 256, 0, stream>>>(x, gt, Wgc, ns, sup, b0);
    k_xout<<<dim3(4, 4, gc), 256, 0, stream>>>(adj, sup, bgc, out, gsum, gsq, b0);
  }

  k_norm<<<2048, 256, 0, stream>>>(gsum, gsq, gn, btn, mask, out);
}

// Round 2
// 830.819 us; speedup vs baseline: 4.5954x; 4.5954x over previous
//
#include <hip/hip_runtime.h>

#define DEVI __device__ __forceinline__

typedef __bf16 bf16x8 __attribute__((ext_vector_type(8)));
typedef float  f32x4  __attribute__((ext_vector_type(4)));
typedef unsigned short ushort8_t __attribute__((ext_vector_type(8)));

constexpr size_t XOUT_ELEMS = (size_t)64 * 512 * 512; // 16,777,216

DEVI unsigned short f2b(float f) {
  __bf16 h = (__bf16)f;               // RNE convert
  return __builtin_bit_cast(unsigned short, h);
}

// ---------------------------------------------------------------------------
// Decode subgraph_sizes (int64 vs int32 layout detection, as round 0 — passed)
// ---------------------------------------------------------------------------
__global__ void k_decode(const int* __restrict__ ss, int* __restrict__ ns) {
  int t = threadIdx.x; // 0..63
  int odd = ss[2 * t + 1];
  unsigned long long bal = __ballot(odd == 0);
  bool is64 = (bal == 0xFFFFFFFFFFFFFFFFull);
  if (is64) {
    const long long* s64 = (const long long*)ss;
    ns[2 * t]     = (int)s64[2 * t];
    ns[2 * t + 1] = (int)s64[2 * t + 1];
  } else {
    ns[2 * t]     = ss[2 * t];
    ns[2 * t + 1] = ss[2 * t + 1];
  }
}

// ---------------------------------------------------------------------------
// gt (f32 for the g_out path) + gth (bf16 for the GEMM1 A operand)
// ---------------------------------------------------------------------------
__global__ void k_gt(const float* __restrict__ gs, const float* __restrict__ W,
                     const float* __restrict__ bias, float* __restrict__ gt,
                     unsigned short* __restrict__ gth) {
  __shared__ float srow[4][512];
  int r0  = blockIdx.y * 4;
  int col = blockIdx.x * 256 + threadIdx.x;
  for (int i = threadIdx.x; i < 4 * 512; i += 256)
    srow[i >> 9][i & 511] = gs[(size_t)r0 * 512 + i];
  __syncthreads();
  float acc[4] = {0.f, 0.f, 0.f, 0.f};
  for (int g = 0; g < 512; ++g) {
    float w = W[(size_t)g * 512 + col];
    acc[0] += srow[0][g] * w;
    acc[1] += srow[1][g] * w;
    acc[2] += srow[2][g] * w;
    acc[3] += srow[3][g] * w;
  }
  float bb = bias[col];
  #pragma unroll
  for (int r = 0; r < 4; ++r) {
    float v = acc[r] + bb;
    gt [(size_t)(r0 + r) * 512 + col] = v;
    gth[(size_t)(r0 + r) * 512 + col] = f2b(v);
  }
}

// ---------------------------------------------------------------------------
// g_out = relu(BN(gt)) -> d_out tail  (unchanged, fp32-exact)
// ---------------------------------------------------------------------------
__global__ void k_gbn(const float* __restrict__ gt, const float* __restrict__ gamma,
                      const float* __restrict__ beta, float* __restrict__ gout) {
  int col = blockIdx.x * 64 + threadIdx.x;
  float s = 0.f, q = 0.f;
  for (int r = 0; r < 128; ++r) {
    float v = gt[(size_t)r * 512 + col];
    s += v; q += v * v;
  }
  float m   = s * (1.f / 128.f);
  float var = q * (1.f / 128.f) - m * m;
  float inv = 1.f / sqrtf(var + 1e-5f);
  float g = gamma[col], b = beta[col];
  for (int r = 0; r < 128; ++r) {
    float v = (gt[(size_t)r * 512 + col] - m) * inv * g + b;
    gout[(size_t)r * 512 + col] = fmaxf(v, 0.f);
  }
}

// ---------------------------------------------------------------------------
// f32 -> bf16 bulk convert (8 elems/thread/iter, 16B stores)
// ---------------------------------------------------------------------------
__global__ void k_cvt(const float* __restrict__ in, unsigned short* __restrict__ out,
                      long n8) {
  long i = (long)blockIdx.x * blockDim.x + threadIdx.x;
  long stride = (long)gridDim.x * blockDim.x;
  for (; i < n8; i += stride) {
    float4 a = ((const float4*)in)[2 * i];
    float4 b = ((const float4*)in)[2 * i + 1];
    ushort8_t o;
    o[0] = f2b(a.x); o[1] = f2b(a.y); o[2] = f2b(a.z); o[3] = f2b(a.w);
    o[4] = f2b(b.x); o[5] = f2b(b.y); o[6] = f2b(b.z); o[7] = f2b(b.w);
    *(ushort8_t*)&out[i * 8] = o;
  }
}

// ---------------------------------------------------------------------------
// W_gc [e][k=1024][o=512] f32  ->  wT [e][o=512][k=1024] bf16 (LDS transpose)
// ---------------------------------------------------------------------------
__global__ void k_cvt_w(const float* __restrict__ W, unsigned short* __restrict__ wT) {
  __shared__ float t[32][33];
  int k0 = blockIdx.x * 32, o0 = blockIdx.y * 32, e = blockIdx.z;
  const float* Wb = W + (size_t)e * 1024 * 512;
  unsigned short* Tb = wT + (size_t)e * 512 * 1024;
  int tid = threadIdx.x;
  #pragma unroll
  for (int p = 0; p < 4; ++p) {
    int kl = p * 8 + (tid >> 5), ol = tid & 31;
    t[kl][ol] = Wb[(size_t)(k0 + kl) * 512 + o0 + ol];
  }
  __syncthreads();
  #pragma unroll
  for (int p = 0; p < 4; ++p) {
    int ol = p * 8 + (tid >> 5), kl = tid & 31;
    Tb[(size_t)(o0 + ol) * 1024 + k0 + kl] = f2b(t[kl][ol]);
  }
}

// ---------------------------------------------------------------------------
// MFMA GEMM core: 128x128 C tile, 4 waves (2x2), BK=32, 16x16x32 bf16 MFMA.
// LDS tiles As/Bs [128 rows][32 k] bf16, XOR-swizzled 16B slots:
//   phys_slot = slot ^ ((row>>1)&3)   (2-way bank aliasing only — free)
// Staging: global_load_lds width 16, LINEAR LDS dest (rule #21), the swizzle
// applied by permuting the per-lane GLOBAL source k-offset.
// 2 barriers per K-step (m97 structure); staging of kt+1 overlaps MFMA of kt.
// ---------------------------------------------------------------------------
DEVI void gl_lds16(const unsigned short* g, unsigned short* l) {
  __builtin_amdgcn_global_load_lds(
      (const __attribute__((address_space(1))) void*)g,
      (__attribute__((address_space(3))) void*)l, 16, 0, 0);
}

DEVI int lds_idx(int row, int slot) {  // ushort index of a 16B slot
  return row * 32 + ((slot ^ ((row >> 1) & 3)) << 3);
}

template <class FA, class FB>
DEVI void mfma_core(unsigned short* As, unsigned short* Bs, FA srcA, FB srcB,
                    int NT, f32x4 (&acc)[4][4]) {
  const int tid  = threadIdx.x;
  const int lane = tid & 63;
  const int wave = tid >> 6;
  const int wr = wave >> 1, wc = wave & 1;
  const int fr = lane & 15, fs = lane >> 4;

  // staging chunks for this thread: c and c+256 (512 x 16B chunks per tile)
  const int c0 = tid,      r0 = c0 >> 2, s0 = (c0 & 3) ^ ((r0 >> 1) & 3);
  const int c1 = tid + 256, r1 = c1 >> 2, s1 = (c1 & 3) ^ ((r1 >> 1) & 3);

  int aoff[4], boff[4];
  #pragma unroll
  for (int i = 0; i < 4; ++i) {
    aoff[i] = lds_idx(wr * 64 + i * 16 + fr, fs);
    boff[i] = lds_idx(wc * 64 + i * 16 + fr, fs);
  }

  gl_lds16(srcA(r0, s0 * 8, 0), As + c0 * 8);
  gl_lds16(srcA(r1, s1 * 8, 0), As + c1 * 8);
  gl_lds16(srcB(r0, s0 * 8, 0), Bs + c0 * 8);
  gl_lds16(srcB(r1, s1 * 8, 0), Bs + c1 * 8);

  for (int kt = 0; kt < NT; ++kt) {
    __syncthreads();                       // staging of kt visible (vmcnt drain)
    bf16x8 af[4], bf[4];
    #pragma unroll
    for (int i = 0; i < 4; ++i) af[i] = *(const bf16x8*)(As + aoff[i]);
    #pragma unroll
    for (int j = 0; j < 4; ++j) bf[j] = *(const bf16x8*)(Bs + boff[j]);
    if (kt + 1 < NT) {
      __syncthreads();                     // all waves done reading (lgkmcnt drained)
      gl_lds16(srcA(r0, s0 * 8, kt + 1), As + c0 * 8);
      gl_lds16(srcA(r1, s1 * 8, kt + 1), As + c1 * 8);
      gl_lds16(srcB(r0, s0 * 8, kt + 1), Bs + c0 * 8);
      gl_lds16(srcB(r1, s1 * 8, kt + 1), Bs + c1 * 8);
    }
    #pragma unroll
    for (int i = 0; i < 4; ++i)
      #pragma unroll
      for (int j = 0; j < 4; ++j)
        acc[i][j] = __builtin_amdgcn_mfma_f32_16x16x32_bf16(af[i], bf[j], acc[i][j], 0, 0, 0);
  }
}

// ---------------------------------------------------------------------------
// GEMM1: support^T[page=gi*4+e][o][m] = ([x|bg][b] @ W_gc[e])^T   (bf16 out)
// A rows synthesized: k<512 from xh, k>=512 from gth row-select / zeros.
// ---------------------------------------------------------------------------
__global__ __launch_bounds__(256) void k_support(
    const unsigned short* __restrict__ xh, const unsigned short* __restrict__ gth,
    const unsigned short* __restrict__ wT, const int* __restrict__ ns,
    const unsigned short* __restrict__ zb, unsigned short* __restrict__ supT, int b0) {
  __shared__ __align__(16) unsigned short As[4096], Bs[4096];
  const int otile = blockIdx.x * 128;
  const int row0  = blockIdx.y * 128;
  const int e  = blockIdx.z & 3;
  const int gi = blockIdx.z >> 2;
  const int b  = b0 + gi;
  const int n1  = ns[2 * b];
  const int n12 = n1 + ns[2 * b + 1];
  const unsigned short* xb = xh + (size_t)b * 512 * 512;
  const unsigned short* g0 = gth + (size_t)(2 * b) * 512;
  const unsigned short* g1 = g0 + 512;
  const unsigned short* wb = wT + (size_t)e * 512 * 1024;

  auto srcA = [=](int row, int kofs, int kt) -> const unsigned short* {
    int k  = kt * 32 + kofs;
    int rg = row0 + row;
    if (k < 512) return xb + (size_t)rg * 512 + k;
    int kk = k - 512;
    if (rg < n1)  return g0 + kk;
    if (rg < n12) return g1 + kk;
    return zb;
  };
  auto srcB = [=](int row, int kofs, int kt) -> const unsigned short* {
    return wb + (size_t)(otile + row) * 1024 + kt * 32 + kofs;
  };

  f32x4 acc[4][4];
  #pragma unroll
  for (int i = 0; i < 4; ++i)
    #pragma unroll
    for (int j = 0; j < 4; ++j) acc[i][j] = (f32x4){0.f, 0.f, 0.f, 0.f};

  mfma_core(As, Bs, srcA, srcB, 32, acc);

  const int lane = threadIdx.x & 63, wave = threadIdx.x >> 6;
  const int wr = wave >> 1, wc = wave & 1, fr = lane & 15, fs = lane >> 4;
  unsigned short* sp = supT + (size_t)(gi * 4 + e) * 262144;
  #pragma unroll
  for (int i = 0; i < 4; ++i) {
    int m = row0 + wr * 64 + i * 16 + fs * 4;      // 4 contiguous m per lane
    #pragma unroll
    for (int j = 0; j < 4; ++j) {
      int o = otile + wc * 64 + j * 16 + fr;
      f32x4 v = acc[i][j];
      ushort4 h;
      h.x = f2b(v[0]); h.y = f2b(v[1]); h.z = f2b(v[2]); h.w = f2b(v[3]);
      *(ushort4*)&sp[(size_t)o * 512 + m] = h;
    }
  }
}

// ---------------------------------------------------------------------------
// GEMM2: out[b][n][o] = sum_{e,m} adj[b,e][n][m] * support^T[e][o][m] + b_gc
// fp32 pre-BN to d_out + per-column sum/sumsq atomics.
// ---------------------------------------------------------------------------
__global__ __launch_bounds__(256) void k_xout(
    const unsigned short* __restrict__ adjh, const unsigned short* __restrict__ supT,
    const float* __restrict__ bgc, float* __restrict__ out,
    float* __restrict__ gsum, float* __restrict__ gsq, int b0) {
  __shared__ __align__(16) unsigned short As[4096], Bs[4096];
  const int otile = blockIdx.x * 128;
  const int row0  = blockIdx.y * 128;
  const int gi = blockIdx.z;
  const int b  = b0 + gi;
  const unsigned short* ab = adjh + (size_t)b * 4 * 262144;
  const unsigned short* sb = supT + (size_t)gi * 4 * 262144;

  auto srcA = [=](int row, int kofs, int kt) -> const unsigned short* {
    int k = kt * 32 + kofs;
    int e = k >> 9, m = k & 511;
    return ab + ((size_t)e * 512 + row0 + row) * 512 + m;
  };
  auto srcB = [=](int row, int kofs, int kt) -> const unsigned short* {
    int k = kt * 32 + kofs;
    int e = k >> 9, m = k & 511;
    return sb + ((size_t)e * 512 + otile + row) * 512 + m;
  };

  f32x4 acc[4][4];
  #pragma unroll
  for (int i = 0; i < 4; ++i)
    #pragma unroll
    for (int j = 0; j < 4; ++j) acc[i][j] = (f32x4){0.f, 0.f, 0.f, 0.f};

  mfma_core(As, Bs, srcA, srcB, 64, acc);

  const int tid = threadIdx.x;
  const int lane = tid & 63, wave = tid >> 6;
  const int wr = wave >> 1, wc = wave & 1, fr = lane & 15, fs = lane >> 4;

  float cs[4], cq[4];
  #pragma unroll
  for (int j = 0; j < 4; ++j) {
    int o = otile + wc * 64 + j * 16 + fr;
    float bb = bgc[o];
    float s = 0.f, q = 0.f;
    #pragma unroll
    for (int i = 0; i < 4; ++i) {
      int nb = row0 + wr * 64 + i * 16 + fs * 4;
      #pragma unroll
      for (int r = 0; r < 4; ++r) {
        float v = acc[i][j][r] + bb;
        out[((size_t)b * 512 + nb + r) * 512 + o] = v;
        s += v; q += v * v;
      }
    }
    cs[j] = s; cq[j] = q;
  }

  __syncthreads();
  float* red = (float*)As;   // reuse LDS: 256 floats
  red[tid] = 0.f;
  __syncthreads();
  #pragma unroll
  for (int j = 0; j < 4; ++j) {
    int cl = wc * 64 + j * 16 + fr;
    atomicAdd(&red[cl], cs[j]);
    atomicAdd(&red[128 + cl], cq[j]);
  }
  __syncthreads();
  if (tid < 128) {
    atomicAdd(&gsum[otile + tid], red[tid]);
    atomicAdd(&gsq[otile + tid],  red[128 + tid]);
  }
}

// ---------------------------------------------------------------------------
// In-place BN + mask + relu (unchanged)
// ---------------------------------------------------------------------------
__global__ void k_norm(const float* __restrict__ gsum, const float* __restrict__ gsq,
                       const float* __restrict__ gamma, const float* __restrict__ beta,
                       const float* __restrict__ mask, float* __restrict__ out) {
  __shared__ float sc[512], sh[512];
  for (int c = threadIdx.x; c < 512; c += blockDim.x) {
    float m   = gsum[c] * (1.f / 32768.f);
    float var = gsq[c] * (1.f / 32768.f) - m * m;
    float inv = 1.f / sqrtf(var + 1e-5f);
    float g = gamma[c] * inv;
    sc[c] = g;
    sh[c] = beta[c] - m * g;
  }
  __syncthreads();
  size_t i0 = (size_t)blockIdx.x * blockDim.x + threadIdx.x;
  size_t stride = (size_t)gridDim.x * blockDim.x;
  size_t n4 = XOUT_ELEMS / 4;
  for (size_t i = i0; i < n4; i += stride) {
    float4 p = ((const float4*)out)[i];
    int c = (int)((i * 4) & 511);
    size_t row = (i * 4) >> 9;
    float mk = mask[row];
    p.x = fmaxf((p.x * sc[c + 0] + sh[c + 0]) * mk, 0.f);
    p.y = fmaxf((p.y * sc[c + 1] + sh[c + 1]) * mk, 0.f);
    p.z = fmaxf((p.z * sc[c + 2] + sh[c + 2]) * mk, 0.f);
    p.w = fmaxf((p.w * sc[c + 3] + sh[c + 3]) * mk, 0.f);
    ((float4*)out)[i] = p;
  }
}

// ---------------------------------------------------------------------------
extern "C" void kernel_launch(void* const* d_in, const int* in_sizes, int n_in,
                              void* d_out, int out_size, void* d_ws, size_t ws_size,
                              hipStream_t stream) {
  const float* x    = (const float*)d_in[0];
  const float* adj  = (const float*)d_in[1];
  const float* gs   = (const float*)d_in[2];
  const int*   ssz  = (const int*)d_in[3];
  const float* mask = (const float*)d_in[4];
  const float* Wgfc = (const float*)d_in[5];
  const float* bgfc = (const float*)d_in[6];
  const float* Wgc  = (const float*)d_in[7];
  const float* bgc  = (const float*)d_in[8];
  const float* gn   = (const float*)d_in[9];
  const float* btn  = (const float*)d_in[10];
  const float* gg   = (const float*)d_in[11];
  const float* btg  = (const float*)d_in[12];
  float* out = (float*)d_out;

  // workspace layout (evidence from round 1: ws_size >= 257 MiB)
  char* w = (char*)d_ws;
  float*          gt   = (float*)w;                        // 256 KiB
  unsigned short* gth  = (unsigned short*)(w + 262144);    // 128 KiB
  int*            ns   = (int*)(w + 393216);               // 512 B
  float*          gsum = (float*)(w + 393728);             // 2 KiB
  float*          gsq  = (float*)(w + 395776);             // 2 KiB
  unsigned short* zb   = (unsigned short*)(w + 397824);    // 1 KiB zeros
  unsigned short* xh   = (unsigned short*)(w + ((size_t)1  << 20));  // 32 MiB
  unsigned short* wT   = (unsigned short*)(w + ((size_t)33 << 20));  // 4 MiB
  unsigned short* adjh = (unsigned short*)(w + ((size_t)37 << 20));  // 128 MiB
  unsigned short* supT = (unsigned short*)(w + ((size_t)165 << 20)); // chunks, 2 MiB/b

  long long avail = (long long)ws_size - (165ll << 20);
  int G = (avail > 0) ? (int)(avail / (2ll << 20)) : 0;
  if (G < 1) G = 1;
  if (G > 64) G = 64;

  k_decode<<<1, 64, 0, stream>>>(ssz, ns);
  k_gt<<<dim3(2, 32), 256, 0, stream>>>(gs, Wgfc, bgfc, gt, gth);
  k_gbn<<<8, 64, 0, stream>>>(gt, gg, btg, out + XOUT_ELEMS);
  hipMemsetAsync(gsum, 0, 5120, stream);  // gsum + gsq + zerobuf (contiguous)

  k_cvt<<<2048, 256, 0, stream>>>(x, xh, (long)(16777216 / 8));
  k_cvt<<<4096, 256, 0, stream>>>(adj, adjh, (long)(67108864 / 8));
  k_cvt_w<<<dim3(32, 16, 4), 256, 0, stream>>>(Wgc, wT);

  for (int b0 = 0; b0 < 64; b0 += G) {
    int gc = 64 - b0; if (gc > G) gc = G;
    k_support<<<dim3(4, 4, 4 * gc), 256, 0, stream>>>(xh, gth, wT, ns, zb, supT, b0);
    k_xout<<<dim3(4, 4, gc), 256, 0, stream>>>(adjh, supT, bgc, out, gsum, gsq, b0);
  }

  k_norm<<<2048, 256, 0, stream>>>(gsum, gsq, gn, btn, mask, out);
}